// Round 4
// baseline (461.760 us; speedup 1.0000x reference)
//
#include <hip/hip_runtime.h>

// Problem constants
#define BB      16384
#define IN_DIM  256
#define NE      32
#define H1D     64
#define H2D     256
#define H3D     128
#define NOUT    128

typedef __bf16 bf16_t;
typedef __bf16 bf16x8  __attribute__((ext_vector_type(8)));
typedef __bf16 bf16x4  __attribute__((ext_vector_type(4)));
typedef float  f32x4   __attribute__((ext_vector_type(4)));
typedef float  f32x16  __attribute__((ext_vector_type(16)));

// ---- workspace layout (bytes): bf16 transposed weights ----
#define OFF_W1  ((size_t)0)                              // W1t: [E][64][256]
#define OFF_W2  (OFF_W1 + (size_t)NE*H1D*IN_DIM*2)       // W2t: [E][256][64]
#define OFF_W3  (OFF_W2 + (size_t)NE*H2D*H1D*2)          // W3t: [E][128][256]
#define OFF_W4  (OFF_W3 + (size_t)NE*H3D*H2D*2)          // W4t: [E][64][128]
#define OFF_W5  (OFF_W4 + (size_t)NE*H1D*H3D*2)          // W5t: [E][128][64]
#define OFF_WG  (OFF_W5 + (size_t)NE*NOUT*H1D*2)         // Wgt: [32][256]

// ---- prep: all weight transposes (incl. Wg) in ONE kernel ----
__global__ void cvt_w_all(const float* __restrict__ W1, const float* __restrict__ W2,
                          const float* __restrict__ W3, const float* __restrict__ W4,
                          const float* __restrict__ W5, const float* __restrict__ Wg,
                          bf16_t* __restrict__ W1t, bf16_t* __restrict__ W2t,
                          bf16_t* __restrict__ W3t, bf16_t* __restrict__ W4t,
                          bf16_t* __restrict__ W5t, bf16_t* __restrict__ Wgt)
{
    __shared__ float tile[64][65];
    const int j = blockIdx.x;
    const int e = j / 21;
    const int q = j % 21;
    const int tid = threadIdx.x;

    if (q == 20) {
        if (e >= 4) return;
        const int kt = e * 64;
        const int tx = tid & 31, ty = tid >> 5;
#pragma unroll
        for (int i = 0; i < 8; i++)
            tile[ty + i * 8][tx] = Wg[(size_t)(kt + ty + i * 8) * 32 + tx];
        __syncthreads();
        const int tx2 = tid & 63, ty2 = tid >> 6;
#pragma unroll
        for (int i = 0; i < 8; i++)
            Wgt[(size_t)(ty2 + i * 4) * 256 + kt + tx2] = (bf16_t)tile[tx2][ty2 + i * 4];
        return;
    }

    const float* src; bf16_t* dst; int K, N, kt, nt;
    if (q < 4)       { K = 256; N = 64;  kt = q * 64;            nt = 0;             src = W1; dst = W1t; }
    else if (q < 8)  { K = 64;  N = 256; kt = 0;                 nt = (q - 4) * 64;  src = W2; dst = W2t; }
    else if (q < 16) { K = 256; N = 128; int r = q - 8; kt = (r >> 1) * 64; nt = (r & 1) * 64; src = W3; dst = W3t; }
    else if (q < 18) { K = 128; N = 64;  kt = (q - 16) * 64;     nt = 0;             src = W4; dst = W4t; }
    else             { K = 64;  N = 128; kt = 0;                 nt = (q - 18) * 64; src = W5; dst = W5t; }
    src += (size_t)e * K * N;
    dst += (size_t)e * K * N;
    const int tx = tid & 63;
    const int ty = tid >> 6;
#pragma unroll
    for (int i = 0; i < 16; i++)
        tile[ty + i * 4][tx] = src[(size_t)(kt + ty + i * 4) * N + nt + tx];
    __syncthreads();
#pragma unroll
    for (int i = 0; i < 16; i++)
        dst[(size_t)(nt + ty + i * 4) * K + kt + tx] = (bf16_t)tile[tx][ty + i * 4];
}

// ---- transposed layer: y^T = Wt-slab · h^T via mfma 32x32x16 ----
// src: LDS h [64][SIN] bf16 row-major. dst: LDS y [64][SOUT].
// Wt: [N][K] bf16 per-expert. Wave computes m-tile `m` (32 rows), n-tiles n0t..n0t+NT-1.
// D^T: batch col = lane&31, feature row = (reg&3)+8*(reg>>2)+4*(lane>>5).
template<int K, int SIN, int SOUT, int NT>
__device__ __forceinline__ void layer_T(const bf16_t* __restrict__ src, bf16_t* __restrict__ dst,
                                        const bf16_t* __restrict__ Wt, const float* __restrict__ bias,
                                        int m, int n0t, int lane31, int half)
{
    constexpr int KS = K / 16;
    constexpr bool SPLIT = (KS >= 8);
    const bf16_t* bp = src + (m * 32 + lane31) * SIN + half * 8;
    f32x16 acc[NT], acc2[NT];
#pragma unroll
    for (int nt = 0; nt < NT; nt++)
#pragma unroll
        for (int r = 0; r < 16; r++) { acc[nt][r] = 0.f; if (SPLIT) acc2[nt][r] = 0.f; }

#pragma unroll
    for (int ks = 0; ks < KS; ks++) {
        const bf16x8 bfrag = *(const bf16x8*)(bp + ks * 16);
#pragma unroll
        for (int nt = 0; nt < NT; nt++) {
            const bf16x8 afrag = *(const bf16x8*)(Wt + (size_t)((n0t + nt) * 32 + lane31) * K
                                                  + ks * 16 + half * 8);
            if (SPLIT && (ks & 1))
                acc2[nt] = __builtin_amdgcn_mfma_f32_32x32x16_bf16(afrag, bfrag, acc2[nt], 0, 0, 0);
            else
                acc[nt]  = __builtin_amdgcn_mfma_f32_32x32x16_bf16(afrag, bfrag, acc[nt], 0, 0, 0);
        }
    }
#pragma unroll
    for (int nt = 0; nt < NT; nt++) {
        if (SPLIT)
#pragma unroll
            for (int r = 0; r < 16; r++) acc[nt][r] += acc2[nt][r];
        bf16_t* dp = dst + (m * 32 + lane31) * SOUT + (n0t + nt) * 32 + half * 4;
#pragma unroll
        for (int q = 0; q < 4; q++) {
            const float4 bq = *(const float4*)(bias + (n0t + nt) * 32 + q * 8 + half * 4);
            bf16x4 o = { (bf16_t)fmaxf(acc[nt][q * 4 + 0] + bq.x, 0.f),
                         (bf16_t)fmaxf(acc[nt][q * 4 + 1] + bq.y, 0.f),
                         (bf16_t)fmaxf(acc[nt][q * 4 + 2] + bq.z, 0.f),
                         (bf16_t)fmaxf(acc[nt][q * 4 + 3] + bq.w, 0.f) };
            *(bf16x4*)(dp + q * 8) = o;
        }
    }
}

// ---- LDS carve (bytes) ----
#define L_SX   0                       // x tile [64][264] bf16 = 33792
#define L_H2   33792                   // h2     [64][264] bf16 = 33792  (aliases gating logits)
#define L_H3   67584                   // h3     [64][136] bf16 = 17408
#define L_H1   84992                   // h1     [64][72]  bf16 = 9216
#define L_H4   94208                   // h4     [64][72]  bf16 = 9216
#define L_SG   103424                  // g      [32][64]  fp32 = 8192
#define L_TOT  111616

__global__ __launch_bounds__(512) void moe_main(
    const float* __restrict__ x,
    const bf16_t* __restrict__ W1t, const bf16_t* __restrict__ W2t,
    const bf16_t* __restrict__ W3t, const bf16_t* __restrict__ W4t,
    const bf16_t* __restrict__ W5t, const bf16_t* __restrict__ Wgt,
    const float* __restrict__ bg,
    const float* __restrict__ b1, const float* __restrict__ b2,
    const float* __restrict__ b3, const float* __restrict__ b4,
    const float* __restrict__ b5, float* __restrict__ out)
{
    __shared__ __align__(16) char lds[L_TOT];
    bf16_t* sX = (bf16_t*)(lds + L_SX);
    bf16_t* h2 = (bf16_t*)(lds + L_H2);
    bf16_t* h3 = (bf16_t*)(lds + L_H3);
    bf16_t* h1 = (bf16_t*)(lds + L_H1);
    bf16_t* h4 = (bf16_t*)(lds + L_H4);
    float*  sLg = (float*)(lds + L_H2);   // gating logits, alias of h2
    float*  sG  = (float*)(lds + L_SG);   // [32 experts][64 rows]

    const int tid    = threadIdx.x;
    const int wave   = tid >> 6;
    const int lane   = tid & 63;
    const int lane31 = lane & 31;
    const int half   = lane >> 5;
    const int lane16 = lane & 15;
    const int quad   = lane >> 4;
    const int b0     = blockIdx.x * 64;

    // ---- stage x: fp32 -> bf16, 64x256 into sX (stride 264) ----
    {
        const int r  = tid >> 3;
        const int c0 = (tid & 7) * 32;
        const float* src = x + (size_t)(b0 + r) * IN_DIM + c0;
        bf16_t* dstp = sX + r * 264 + c0;
#pragma unroll
        for (int jj = 0; jj < 4; jj++) {
            const float4 v0 = *(const float4*)(src + jj * 8);
            const float4 v1 = *(const float4*)(src + jj * 8 + 4);
            bf16x8 o = { (bf16_t)v0.x, (bf16_t)v0.y, (bf16_t)v0.z, (bf16_t)v0.w,
                         (bf16_t)v1.x, (bf16_t)v1.y, (bf16_t)v1.z, (bf16_t)v1.w };
            *(bf16x8*)(dstp + jj * 8) = o;
        }
    }
    __syncthreads();

    // ---- gating: logits via 16x16x32 MFMA -> sLg, softmax -> sG[32][64] ----
    {
        const int m  = wave >> 1;
        const int nt = wave & 1;
        bf16x8 b[8], a[8];
        const bf16_t* wp = Wgt + (size_t)(nt * 16 + lane16) * 256 + quad * 8;
        const bf16_t* ap = sX + (m * 16 + lane16) * 264 + quad * 8;
#pragma unroll
        for (int ks = 0; ks < 8; ks++) { b[ks] = *(const bf16x8*)(wp + ks * 32);
                                         a[ks] = *(const bf16x8*)(ap + ks * 32); }
        f32x4 acc = (f32x4){0.f, 0.f, 0.f, 0.f};
#pragma unroll
        for (int ks = 0; ks < 8; ks++)
            acc = __builtin_amdgcn_mfma_f32_16x16x32_bf16(a[ks], b[ks], acc, 0, 0, 0);
        const int col = nt * 16 + lane16;
        const float bgv = bg[col];
#pragma unroll
        for (int r = 0; r < 4; r++)
            sLg[(m * 16 + quad * 4 + r) * 33 + col] = acc[r] + bgv;
    }
    __syncthreads();
    {
        const int row = tid >> 3;
        const int c0  = (tid & 7) * 4;
        float l[4];
#pragma unroll
        for (int jj = 0; jj < 4; jj++) l[jj] = sLg[row * 33 + c0 + jj];
        float mx = fmaxf(fmaxf(l[0], l[1]), fmaxf(l[2], l[3]));
#pragma unroll
        for (int off = 1; off < 8; off <<= 1) mx = fmaxf(mx, __shfl_xor(mx, off));
        float ex[4], sm = 0.f;
#pragma unroll
        for (int jj = 0; jj < 4; jj++) { ex[jj] = __expf(l[jj] - mx); sm += ex[jj]; }
#pragma unroll
        for (int off = 1; off < 8; off <<= 1) sm += __shfl_xor(sm, off);
        const float rs = 1.f / sm;
#pragma unroll
        for (int jj = 0; jj < 4; jj++) sG[(c0 + jj) * 64 + row] = ex[jj] * rs;
    }
    __syncthreads();

    // gated output accumulator (held by waves 4..7: 2 n-tiles of 32 cols x 32 rows)
    float oacc[2][16];
#pragma unroll
    for (int nt = 0; nt < 2; nt++)
#pragma unroll
        for (int r = 0; r < 16; r++) oacc[nt][r] = 0.f;

    // L5(ep) gated accumulate for waves 4..7
    auto l5_accum = [&](int ep) {
        const int wl  = wave - 4;
        const int m   = wl & 1;
        const int n0t = (wl >> 1) * 2;
        const bf16_t* W5e = W5t + (size_t)ep * (NOUT * H1D);
        const float*  b5e = b5 + ep * NOUT;
        const float gv = sG[ep * 64 + m * 32 + lane31];
        const bf16_t* bp = h4 + (m * 32 + lane31) * 72 + half * 8;
#pragma unroll
        for (int nt = 0; nt < 2; nt++) {
            f32x16 acc;
#pragma unroll
            for (int r = 0; r < 16; r++) acc[r] = 0.f;
#pragma unroll
            for (int ks = 0; ks < 4; ks++) {
                const bf16x8 bfrag = *(const bf16x8*)(bp + ks * 16);
                const bf16x8 afrag = *(const bf16x8*)(W5e + (size_t)((n0t + nt) * 32 + lane31) * H1D
                                                      + ks * 16 + half * 8);
                acc = __builtin_amdgcn_mfma_f32_32x32x16_bf16(afrag, bfrag, acc, 0, 0, 0);
            }
#pragma unroll
            for (int q = 0; q < 4; q++) {
                const float4 bq = *(const float4*)(b5e + (n0t + nt) * 32 + q * 8 + half * 4);
                oacc[nt][q * 4 + 0] += gv * (acc[q * 4 + 0] + bq.x);
                oacc[nt][q * 4 + 1] += gv * (acc[q * 4 + 1] + bq.y);
                oacc[nt][q * 4 + 2] += gv * (acc[q * 4 + 2] + bq.z);
                oacc[nt][q * 4 + 3] += gv * (acc[q * 4 + 3] + bq.w);
            }
        }
    };

    for (int e = 0; e < NE; e++) {
        // Phase A: waves 0-3: L1(e) x->h1 ; waves 4-7: L5(e-1) h4->oacc
        if (wave < 4)
            layer_T<256, 264, 72, 1>(sX, h1, W1t + (size_t)e * (H1D * IN_DIM),
                                     b1 + e * H1D, wave & 1, wave >> 1, lane31, half);
        else if (e > 0)
            l5_accum(e - 1);
        __syncthreads();
        // Phase B: L2 h1->h2 (all 8 waves, NT=2)
        layer_T<64, 72, 264, 2>(h1, h2, W2t + (size_t)e * (H2D * H1D),
                                b2 + e * H2D, wave & 1, (wave >> 1) * 2, lane31, half);
        __syncthreads();
        // Phase C: L3 h2->h3 (all 8 waves)
        layer_T<256, 264, 136, 1>(h2, h3, W3t + (size_t)e * (H3D * H2D),
                                  b3 + e * H3D, wave & 1, wave >> 1, lane31, half);
        __syncthreads();
        // Phase D: waves 0-3: L4 h3->h4
        if (wave < 4)
            layer_T<128, 136, 72, 1>(h3, h4, W4t + (size_t)e * (H1D * H3D),
                                     b4 + e * H1D, wave & 1, wave >> 1, lane31, half);
        __syncthreads();
    }

    if (wave >= 4) {
        l5_accum(NE - 1);
        const int wl  = wave - 4;
        const int m   = wl & 1;
        const int n0t = (wl >> 1) * 2;
        float* op = out + (size_t)(b0 + m * 32 + lane31) * NOUT;
#pragma unroll
        for (int nt = 0; nt < 2; nt++)
#pragma unroll
            for (int q = 0; q < 4; q++) {
                float4 v = { oacc[nt][q * 4 + 0], oacc[nt][q * 4 + 1],
                             oacc[nt][q * 4 + 2], oacc[nt][q * 4 + 3] };
                *(float4*)(op + (n0t + nt) * 32 + q * 8 + half * 4) = v;
            }
    }
}

extern "C" void kernel_launch(void* const* d_in, const int* in_sizes, int n_in,
                              void* d_out, int out_size, void* d_ws, size_t ws_size,
                              hipStream_t stream)
{
    (void)in_sizes; (void)n_in; (void)out_size; (void)ws_size;
    const float* x  = (const float*)d_in[0];
    const float* Wg = (const float*)d_in[1];
    const float* bg = (const float*)d_in[2];
    const float* W1 = (const float*)d_in[3];
    const float* b1 = (const float*)d_in[4];
    const float* W2 = (const float*)d_in[5];
    const float* b2 = (const float*)d_in[6];
    const float* W3 = (const float*)d_in[7];
    const float* b3 = (const float*)d_in[8];
    const float* W4 = (const float*)d_in[9];
    const float* b4 = (const float*)d_in[10];
    const float* W5 = (const float*)d_in[11];
    const float* b5 = (const float*)d_in[12];

    char* ws = (char*)d_ws;
    bf16_t* W1t = (bf16_t*)(ws + OFF_W1);
    bf16_t* W2t = (bf16_t*)(ws + OFF_W2);
    bf16_t* W3t = (bf16_t*)(ws + OFF_W3);
    bf16_t* W4t = (bf16_t*)(ws + OFF_W4);
    bf16_t* W5t = (bf16_t*)(ws + OFF_W5);
    bf16_t* Wgt = (bf16_t*)(ws + OFF_WG);
    float*  out = (float*)d_out;

    cvt_w_all<<<dim3(NE * 21), dim3(256), 0, stream>>>(W1, W2, W3, W4, W5, Wg,
                                                       W1t, W2t, W3t, W4t, W5t, Wgt);
    moe_main<<<dim3(256), dim3(512), 0, stream>>>(x, W1t, W2t, W3t, W4t, W5t, Wgt, bg,
                                                  b1, b2, b3, b4, b5, out);
}

// Round 5
// 433.186 us; speedup vs baseline: 1.0660x; 1.0660x over previous
//
#include <hip/hip_runtime.h>

// Problem constants
#define BB      16384
#define IN_DIM  256
#define NE      32
#define H1D     64
#define H2D     256
#define H3D     128
#define NOUT    128

typedef __bf16 bf16_t;
typedef __bf16 bf16x8  __attribute__((ext_vector_type(8)));
typedef float  f32x4   __attribute__((ext_vector_type(4)));

// ---- workspace layout (bytes): bf16 transposed weights ----
#define OFF_W1  ((size_t)0)                              // W1t: [E][64][256]
#define OFF_W2  (OFF_W1 + (size_t)NE*H1D*IN_DIM*2)       // W2t: [E][256][64]
#define OFF_W3  (OFF_W2 + (size_t)NE*H2D*H1D*2)          // W3t: [E][128][256]
#define OFF_W4  (OFF_W3 + (size_t)NE*H3D*H2D*2)          // W4t: [E][64][128]
#define OFF_W5  (OFF_W4 + (size_t)NE*H1D*H3D*2)          // W5t: [E][128][64]
#define OFF_WG  (OFF_W5 + (size_t)NE*NOUT*H1D*2)         // Wgt: [32][256]

// ---- prep: all weight transposes (incl. Wg) in ONE kernel ----
__global__ void cvt_w_all(const float* __restrict__ W1, const float* __restrict__ W2,
                          const float* __restrict__ W3, const float* __restrict__ W4,
                          const float* __restrict__ W5, const float* __restrict__ Wg,
                          bf16_t* __restrict__ W1t, bf16_t* __restrict__ W2t,
                          bf16_t* __restrict__ W3t, bf16_t* __restrict__ W4t,
                          bf16_t* __restrict__ W5t, bf16_t* __restrict__ Wgt)
{
    __shared__ float tile[64][65];
    const int j = blockIdx.x;
    const int e = j / 21;
    const int q = j % 21;
    const int tid = threadIdx.x;

    if (q == 20) {
        if (e >= 4) return;
        const int kt = e * 64;
        const int tx = tid & 31, ty = tid >> 5;
#pragma unroll
        for (int i = 0; i < 8; i++)
            tile[ty + i * 8][tx] = Wg[(size_t)(kt + ty + i * 8) * 32 + tx];
        __syncthreads();
        const int tx2 = tid & 63, ty2 = tid >> 6;
#pragma unroll
        for (int i = 0; i < 8; i++)
            Wgt[(size_t)(ty2 + i * 4) * 256 + kt + tx2] = (bf16_t)tile[tx2][ty2 + i * 4];
        return;
    }

    const float* src; bf16_t* dst; int K, N, kt, nt;
    if (q < 4)       { K = 256; N = 64;  kt = q * 64;            nt = 0;             src = W1; dst = W1t; }
    else if (q < 8)  { K = 64;  N = 256; kt = 0;                 nt = (q - 4) * 64;  src = W2; dst = W2t; }
    else if (q < 16) { K = 256; N = 128; int r = q - 8; kt = (r >> 1) * 64; nt = (r & 1) * 64; src = W3; dst = W3t; }
    else if (q < 18) { K = 128; N = 64;  kt = (q - 16) * 64;     nt = 0;             src = W4; dst = W4t; }
    else             { K = 64;  N = 128; kt = 0;                 nt = (q - 18) * 64; src = W5; dst = W5t; }
    src += (size_t)e * K * N;
    dst += (size_t)e * K * N;
    const int tx = tid & 63;
    const int ty = tid >> 6;
#pragma unroll
    for (int i = 0; i < 16; i++)
        tile[ty + i * 4][tx] = src[(size_t)(kt + ty + i * 4) * N + nt + tx];
    __syncthreads();
#pragma unroll
    for (int i = 0; i < 16; i++)
        dst[(size_t)(nt + ty + i * 4) * K + kt + tx] = (bf16_t)tile[tx][ty + i * 4];
}

// ---- MFMA layer piece (16x16x32): MT m-tiles from m0, NT n-tiles from n0t ----
// Weights loaded UPFRONT into registers (batched, latency overlapped), then MFMA.
template<int K, int SIN, int SOUT, int MT, int NT>
__device__ __forceinline__ void layerM(const bf16_t* __restrict__ src, bf16_t* __restrict__ dst,
                                       const bf16_t* __restrict__ Wt, const float* __restrict__ bias,
                                       int m0, int n0t, int lane16, int quad)
{
    constexpr int KS = K / 32;
    bf16x8 b[NT][KS];
#pragma unroll
    for (int nt = 0; nt < NT; nt++) {
        const bf16_t* wp = Wt + (size_t)((n0t + nt) * 16 + lane16) * K + quad * 8;
#pragma unroll
        for (int ks = 0; ks < KS; ks++) b[nt][ks] = *(const bf16x8*)(wp + ks * 32);
    }
#pragma unroll
    for (int m = 0; m < MT; m++) {
        bf16x8 a[KS];
        const bf16_t* ap = src + ((m0 + m) * 16 + lane16) * SIN + quad * 8;
#pragma unroll
        for (int ks = 0; ks < KS; ks++) a[ks] = *(const bf16x8*)(ap + ks * 32);
        f32x4 acc[NT];
#pragma unroll
        for (int nt = 0; nt < NT; nt++) acc[nt] = (f32x4){0.f, 0.f, 0.f, 0.f};
#pragma unroll
        for (int nt = 0; nt < NT; nt++)
#pragma unroll
            for (int ks = 0; ks < KS; ks++)
                acc[nt] = __builtin_amdgcn_mfma_f32_16x16x32_bf16(a[ks], b[nt][ks], acc[nt], 0, 0, 0);
#pragma unroll
        for (int nt = 0; nt < NT; nt++) {
            const int col = (n0t + nt) * 16 + lane16;
            const float bv = bias[col];
#pragma unroll
            for (int r = 0; r < 4; r++)
                dst[((m0 + m) * 16 + quad * 4 + r) * SOUT + col] =
                    (bf16_t)fmaxf(acc[nt][r] + bv, 0.f);
        }
    }
}

// ---- LDS carve (bytes), M=32 tiles ----
#define L_SX   0                       // x tile [32][264] bf16 = 16896
#define L_H2   16896                   // h2     [32][264] bf16 = 16896  (aliases gating logits)
#define L_H3   33792                   // h3     [32][136] bf16 = 8704
#define L_H1   42496                   // h1     [32][72]  bf16 = 4608
#define L_H4   47104                   // h4     [32][72]  bf16 = 4608
#define L_SG   51712                   // g      [32 exp][32 rows] fp32 = 4096
#define L_TOT  55808

// ---- main: 32-row tile, 512 blocks (2/CU), in-kernel gating, 4 barriers/expert ----
__global__ __launch_bounds__(512, 4) void moe_main(
    const float* __restrict__ x,
    const bf16_t* __restrict__ W1t, const bf16_t* __restrict__ W2t,
    const bf16_t* __restrict__ W3t, const bf16_t* __restrict__ W4t,
    const bf16_t* __restrict__ W5t, const bf16_t* __restrict__ Wgt,
    const float* __restrict__ bg,
    const float* __restrict__ b1, const float* __restrict__ b2,
    const float* __restrict__ b3, const float* __restrict__ b4,
    const float* __restrict__ b5, float* __restrict__ out)
{
    __shared__ __align__(16) char lds[L_TOT];
    bf16_t* sX = (bf16_t*)(lds + L_SX);
    bf16_t* h2 = (bf16_t*)(lds + L_H2);
    bf16_t* h3 = (bf16_t*)(lds + L_H3);
    bf16_t* h1 = (bf16_t*)(lds + L_H1);
    bf16_t* h4 = (bf16_t*)(lds + L_H4);
    float*  sLg = (float*)(lds + L_H2);   // gating logits [32][33], alias of h2
    float*  sG  = (float*)(lds + L_SG);   // [32 experts][32 rows]

    const int tid    = threadIdx.x;
    const int wave   = tid >> 6;
    const int lane   = tid & 63;
    const int lane16 = lane & 15;
    const int quad   = lane >> 4;
    const int b0     = blockIdx.x * 32;

    // ---- stage x: fp32 -> bf16, 32x256 into sX (stride 264) ----
    {
        const int r  = tid >> 4;
        const int c0 = (tid & 15) * 16;
        const float* src = x + (size_t)(b0 + r) * IN_DIM + c0;
        bf16_t* dstp = sX + r * 264 + c0;
#pragma unroll
        for (int jj = 0; jj < 2; jj++) {
            const float4 v0 = *(const float4*)(src + jj * 8);
            const float4 v1 = *(const float4*)(src + jj * 8 + 4);
            bf16x8 o = { (bf16_t)v0.x, (bf16_t)v0.y, (bf16_t)v0.z, (bf16_t)v0.w,
                         (bf16_t)v1.x, (bf16_t)v1.y, (bf16_t)v1.z, (bf16_t)v1.w };
            *(bf16x8*)(dstp + jj * 8) = o;
        }
    }
    __syncthreads();

    // ---- gating: logits via MFMA (waves 0-3) -> sLg, softmax -> sG ----
    if (wave < 4) {
        const int m  = wave & 1;
        const int nt = wave >> 1;
        bf16x8 b[8], a[8];
        const bf16_t* wp = Wgt + (size_t)(nt * 16 + lane16) * 256 + quad * 8;
        const bf16_t* ap = sX + (m * 16 + lane16) * 264 + quad * 8;
#pragma unroll
        for (int ks = 0; ks < 8; ks++) { b[ks] = *(const bf16x8*)(wp + ks * 32);
                                         a[ks] = *(const bf16x8*)(ap + ks * 32); }
        f32x4 acc = (f32x4){0.f, 0.f, 0.f, 0.f};
#pragma unroll
        for (int ks = 0; ks < 8; ks++)
            acc = __builtin_amdgcn_mfma_f32_16x16x32_bf16(a[ks], b[ks], acc, 0, 0, 0);
        const int col = nt * 16 + lane16;
        const float bgv = bg[col];
#pragma unroll
        for (int r = 0; r < 4; r++)
            sLg[(m * 16 + quad * 4 + r) * 33 + col] = acc[r] + bgv;
    }
    __syncthreads();
    if (tid < 256) {
        const int row = tid >> 3;
        const int c0  = (tid & 7) * 4;
        float l[4];
#pragma unroll
        for (int jj = 0; jj < 4; jj++) l[jj] = sLg[row * 33 + c0 + jj];
        float mx = fmaxf(fmaxf(l[0], l[1]), fmaxf(l[2], l[3]));
#pragma unroll
        for (int off = 1; off < 8; off <<= 1) mx = fmaxf(mx, __shfl_xor(mx, off));
        float ex[4], sm = 0.f;
#pragma unroll
        for (int jj = 0; jj < 4; jj++) { ex[jj] = __expf(l[jj] - mx); sm += ex[jj]; }
#pragma unroll
        for (int off = 1; off < 8; off <<= 1) sm += __shfl_xor(sm, off);
        const float rs = 1.f / sm;
#pragma unroll
        for (int jj = 0; jj < 4; jj++) sG[(c0 + jj) * 32 + row] = ex[jj] * rs;
    }
    __syncthreads();

    // gated output accumulator: waves 4-7, cols (wave-4)*32..+31, all 32 rows
    float oacc[2][2][4];
#pragma unroll
    for (int m = 0; m < 2; m++)
#pragma unroll
        for (int nt = 0; nt < 2; nt++)
#pragma unroll
            for (int r = 0; r < 4; r++) oacc[m][nt][r] = 0.f;

    // L5(ep) gated accumulate for waves 4-7: MT=2, NT=2, K=64
    auto l5_accum = [&](int ep) {
        const int n0t = (wave - 4) * 2;
        const bf16_t* W5e = W5t + (size_t)ep * (NOUT * H1D);
        const float*  b5e = b5 + ep * NOUT;
        bf16x8 b[2][2];
#pragma unroll
        for (int nt = 0; nt < 2; nt++) {
            const bf16_t* wp = W5e + (size_t)((n0t + nt) * 16 + lane16) * H1D + quad * 8;
#pragma unroll
            for (int ks = 0; ks < 2; ks++) b[nt][ks] = *(const bf16x8*)(wp + ks * 32);
        }
#pragma unroll
        for (int m = 0; m < 2; m++) {
            bf16x8 a[2];
            const bf16_t* ap = h4 + (m * 16 + lane16) * 72 + quad * 8;
#pragma unroll
            for (int ks = 0; ks < 2; ks++) a[ks] = *(const bf16x8*)(ap + ks * 32);
#pragma unroll
            for (int nt = 0; nt < 2; nt++) {
                f32x4 acc = (f32x4){0.f, 0.f, 0.f, 0.f};
#pragma unroll
                for (int ks = 0; ks < 2; ks++)
                    acc = __builtin_amdgcn_mfma_f32_16x16x32_bf16(a[ks], b[nt][ks], acc, 0, 0, 0);
                const float bv = b5e[(n0t + nt) * 16 + lane16];
#pragma unroll
                for (int r = 0; r < 4; r++) {
                    const float gv = sG[ep * 32 + m * 16 + quad * 4 + r];
                    oacc[m][nt][r] += gv * (acc[r] + bv);
                }
            }
        }
    };

    for (int e = 0; e < NE; e++) {
        // Phase A: waves 0-3: L1 (nt=wave, MT=2) ; waves 4-7: L5(e-1)
        if (wave < 4)
            layerM<256, 264, 72, 2, 1>(sX, h1, W1t + (size_t)e * (H1D * IN_DIM),
                                       b1 + e * H1D, 0, wave, lane16, quad);
        else if (e > 0)
            l5_accum(e - 1);
        __syncthreads();
        // Phase B: L2 (all 8 waves, NT=2, n0t=wave*2, MT=2)
        layerM<64, 72, 264, 2, 2>(h1, h2, W2t + (size_t)e * (H2D * H1D),
                                  b2 + e * H2D, 0, wave * 2, lane16, quad);
        __syncthreads();
        // Phase C: L3 (all 8 waves, NT=1, n0t=wave, MT=2)
        layerM<256, 264, 136, 2, 1>(h2, h3, W3t + (size_t)e * (H3D * H2D),
                                    b3 + e * H3D, 0, wave, lane16, quad);
        __syncthreads();
        // Phase D: L4 (all 8 waves, m=wave&1, nt=wave>>1, MT=1)
        layerM<128, 136, 72, 1, 1>(h3, h4, W4t + (size_t)e * (H1D * H3D),
                                   b4 + e * H1D, wave & 1, wave >> 1, lane16, quad);
        __syncthreads();
    }

    // Final L5(31) + output store (waves 4-7)
    if (wave >= 4) {
        l5_accum(NE - 1);
        const int n0t = (wave - 4) * 2;
#pragma unroll
        for (int m = 0; m < 2; m++)
#pragma unroll
            for (int nt = 0; nt < 2; nt++)
#pragma unroll
                for (int r = 0; r < 4; r++)
                    out[(size_t)(b0 + m * 16 + quad * 4 + r) * NOUT + (n0t + nt) * 16 + lane16] =
                        oacc[m][nt][r];
    }
}

extern "C" void kernel_launch(void* const* d_in, const int* in_sizes, int n_in,
                              void* d_out, int out_size, void* d_ws, size_t ws_size,
                              hipStream_t stream)
{
    (void)in_sizes; (void)n_in; (void)out_size; (void)ws_size;
    const float* x  = (const float*)d_in[0];
    const float* Wg = (const float*)d_in[1];
    const float* bg = (const float*)d_in[2];
    const float* W1 = (const float*)d_in[3];
    const float* b1 = (const float*)d_in[4];
    const float* W2 = (const float*)d_in[5];
    const float* b2 = (const float*)d_in[6];
    const float* W3 = (const float*)d_in[7];
    const float* b3 = (const float*)d_in[8];
    const float* W4 = (const float*)d_in[9];
    const float* b4 = (const float*)d_in[10];
    const float* W5 = (const float*)d_in[11];
    const float* b5 = (const float*)d_in[12];

    char* ws = (char*)d_ws;
    bf16_t* W1t = (bf16_t*)(ws + OFF_W1);
    bf16_t* W2t = (bf16_t*)(ws + OFF_W2);
    bf16_t* W3t = (bf16_t*)(ws + OFF_W3);
    bf16_t* W4t = (bf16_t*)(ws + OFF_W4);
    bf16_t* W5t = (bf16_t*)(ws + OFF_W5);
    bf16_t* Wgt = (bf16_t*)(ws + OFF_WG);
    float*  out = (float*)d_out;

    cvt_w_all<<<dim3(NE * 21), dim3(256), 0, stream>>>(W1, W2, W3, W4, W5, Wg,
                                                       W1t, W2t, W3t, W4t, W5t, Wgt);
    moe_main<<<dim3(512), dim3(512), 0, stream>>>(x, W1t, W2t, W3t, W4t, W5t, Wgt, bg,
                                                  b1, b2, b3, b4, b5, out);
}